// Round 5
// baseline (1413.363 us; speedup 1.0000x reference)
//
#include <hip/hip_runtime.h>
#include <hip/hip_bf16.h>
#include <hip/hip_cooperative_groups.h>

namespace cg = cooperative_groups;

// Problem constants (match reference)
#define NN   8192      // nodes
#define NE   524288    // edges
#define DH   16384     // 2N hidden
#define NOUT 32

#define NBLK 1024                  // cooperative grid: 4 blocks/CU on 256 CUs
#define NTHR 256
#define NT   (NBLK * NTHR)         // 262144 threads; NE = 2*NT exactly
#define NWAVE (NBLK * 4)           // 4096 waves; NN = 2*NWAVE exactly

typedef float f32x4 __attribute__((ext_vector_type(4)));

// ---------------------------------------------------------------------------
// One cooperative kernel for the whole GCN chain.
// Phases: P0 zero-cnt + h1 | P1 hist | P2 scan (block 0) | P3 CSR build |
//         P4 g4 (L1 agg+relu+W2) | P5 g2 (L2 agg+relu+W3) | P6 g1 -> v
// dst[e] cached in regs across P1/P3; row[] cached across P4/P5/P6.
// ---------------------------------------------------------------------------

__global__ __launch_bounds__(256, 4) void k_gcn(
    const float* __restrict__ data,
    const float* __restrict__ W1, const float* __restrict__ b1,
    const float* __restrict__ W2, const float* __restrict__ b2,
    const float* __restrict__ W3, const float* __restrict__ b3,
    const int* __restrict__ src, const int* __restrict__ dst,
    int* cnt, int* row, int* cursor, int* srcs,
    float* dinv, float* h1, float* h2, float* h3, float* v)
{
    cg::grid_group grid = cg::this_grid();
    const int tid  = blockIdx.x * NTHR + threadIdx.x;
    const int wid  = threadIdx.x >> 6;
    const int lane = threadIdx.x & 63;
    const int gw   = blockIdx.x * 4 + wid;       // global wave id [0, 4096)

    // ---- P0: zero cnt + h1 = x0 @ W1.T ----
    if (tid < NN) {
        cnt[tid] = 0;
        float a = data[2 * tid], b = data[2 * tid + 1];
        float4 h;
        h.x = a * W1[0] + b * W1[1];
        h.y = a * W1[2] + b * W1[3];
        h.z = a * W1[4] + b * W1[5];
        h.w = a * W1[6] + b * W1[7];
        *(float4*)(h1 + 4 * tid) = h;
    }
    // preload this thread's two edges (inputs are constant — safe pre-sync)
    const int e0 = tid, e1 = tid + NT;
    const int d0 = dst[e0], d1 = dst[e1];
    grid.sync();

    // ---- P1: degree histogram (int atomics) ----
    atomicAdd(&cnt[d0], 1);
    atomicAdd(&cnt[d1], 1);
    grid.sync();

    // ---- P2: exclusive scan + dinv (block 0 only; 256 thr x 32 elems) ----
    if (blockIdx.x == 0) {
        __shared__ int sm[256];
        int t = threadIdx.x, base = t * 32;
        int local[32], sum = 0;
#pragma unroll
        for (int k = 0; k < 32; ++k) { local[k] = cnt[base + k]; sum += local[k]; }
        sm[t] = sum;
        __syncthreads();
        for (int off = 1; off < 256; off <<= 1) {
            int vv = (t >= off) ? sm[t - off] : 0;
            __syncthreads();
            sm[t] += vv;
            __syncthreads();
        }
        int pre = (t == 0) ? 0 : sm[t - 1];
#pragma unroll
        for (int k = 0; k < 32; ++k) {
            row[base + k] = pre;
            cursor[base + k] = pre;
            dinv[base + k] = rsqrtf((float)local[k] + 1.0f);
            pre += local[k];
        }
        if (t == 255) row[NN] = pre;   // == NE
    }
    grid.sync();

    // ---- P3: CSR build (counting-sort placement) ----
    {
        int s0 = src[e0], s1 = src[e1];
        int p0 = atomicAdd(&cursor[d0], 1); srcs[p0] = s0;
        int p1 = atomicAdd(&cursor[d1], 1); srcs[p1] = s1;
    }
    grid.sync();

    // node ranges for the gather phases (2 nodes per wave), cached once
    const int i0 = gw, i1 = gw + NWAVE;
    const int beg0 = row[i0], end0 = row[i0 + 1];
    const int beg1 = row[i1], end1 = row[i1 + 1];

    // ---- P4: layer1 gather (C=4) + relu + W2 -> h2 ----
#pragma unroll
    for (int r = 0; r < 2; ++r) {
        int i = r ? i1 : i0, beg = r ? beg1 : beg0, end = r ? end1 : end0;
        float a0 = 0, a1 = 0, a2 = 0, a3 = 0;
        for (int p = beg + lane; p < end; p += 64) {
            int s = srcs[p];
            float w = dinv[s];
            float4 hv = *(const float4*)(h1 + 4 * s);
            a0 += w * hv.x; a1 += w * hv.y; a2 += w * hv.z; a3 += w * hv.w;
        }
#pragma unroll
        for (int off = 32; off > 0; off >>= 1) {
            a0 += __shfl_down(a0, off, 64);
            a1 += __shfl_down(a1, off, 64);
            a2 += __shfl_down(a2, off, 64);
            a3 += __shfl_down(a3, off, 64);
        }
        if (lane == 0) {
            float di = dinv[i];
            float4 hs = *(const float4*)(h1 + 4 * i);
            float x0v = fmaxf(di * (a0 + di * hs.x) + b1[0], 0.0f);
            float x1v = fmaxf(di * (a1 + di * hs.y) + b1[1], 0.0f);
            float x2v = fmaxf(di * (a2 + di * hs.z) + b1[2], 0.0f);
            float x3v = fmaxf(di * (a3 + di * hs.w) + b1[3], 0.0f);
            float2 o;
            o.x = x0v * W2[0] + x1v * W2[1] + x2v * W2[2] + x3v * W2[3];
            o.y = x0v * W2[4] + x1v * W2[5] + x2v * W2[6] + x3v * W2[7];
            *(float2*)(h2 + 2 * i) = o;
        }
    }
    grid.sync();

    // ---- P5: layer2 gather (C=2) + relu + W3 -> h3 ----
#pragma unroll
    for (int r = 0; r < 2; ++r) {
        int i = r ? i1 : i0, beg = r ? beg1 : beg0, end = r ? end1 : end0;
        float a0 = 0, a1 = 0;
        for (int p = beg + lane; p < end; p += 64) {
            int s = srcs[p];
            float w = dinv[s];
            float2 hv = *(const float2*)(h2 + 2 * s);
            a0 += w * hv.x; a1 += w * hv.y;
        }
#pragma unroll
        for (int off = 32; off > 0; off >>= 1) {
            a0 += __shfl_down(a0, off, 64);
            a1 += __shfl_down(a1, off, 64);
        }
        if (lane == 0) {
            float di = dinv[i];
            float2 hs = *(const float2*)(h2 + 2 * i);
            float x0v = fmaxf(di * (a0 + di * hs.x) + b2[0], 0.0f);
            float x1v = fmaxf(di * (a1 + di * hs.y) + b2[1], 0.0f);
            h3[i] = x0v * W3[0] + x1v * W3[1];
        }
    }
    grid.sync();

    // ---- P6: layer3 gather (C=1) -> v ----
#pragma unroll
    for (int r = 0; r < 2; ++r) {
        int i = r ? i1 : i0, beg = r ? beg1 : beg0, end = r ? end1 : end0;
        float a0 = 0;
        for (int p = beg + lane; p < end; p += 64) {
            int s = srcs[p];
            a0 += dinv[s] * h3[s];
        }
#pragma unroll
        for (int off = 32; off > 0; off >>= 1) a0 += __shfl_down(a0, off, 64);
        if (lane == 0) {
            float di = dinv[i];
            v[i] = di * (a0 + di * h3[i]) + b3[0];
        }
    }
}

// ---------------------------------------------------------------------------
// Trailing MLP: one wave per row, shuffle reduce, non-temporal weight stream.
// ---------------------------------------------------------------------------

__global__ __launch_bounds__(256) void k_mv1(const float* __restrict__ v,
                                             const float* __restrict__ Wa,
                                             const float* __restrict__ ba,
                                             float* __restrict__ y) {
    int wid  = threadIdx.x >> 6;
    int lane = threadIdx.x & 63;
    int j = blockIdx.x * 4 + wid;                 // row of Wa
    const f32x4* wr = (const f32x4*)(Wa + (size_t)j * NN);
    const f32x4* vv = (const f32x4*)v;
    float acc = 0.0f;
#pragma unroll 8
    for (int it = 0; it < (NN / 4) / 64; ++it) {  // 32 iters
        int idx = it * 64 + lane;                 // wave reads 1 KB contiguous
        f32x4 w = __builtin_nontemporal_load(&wr[idx]);   // Wa streamed once, 2x LLC
        f32x4 x = vv[idx];
        acc += w.x * x.x + w.y * x.y + w.z * x.z + w.w * x.w;
    }
#pragma unroll
    for (int off = 32; off > 0; off >>= 1) acc += __shfl_down(acc, off, 64);
    if (lane == 0) y[j] = tanhf(acc + ba[j]);
}

__global__ __launch_bounds__(256) void k_mv2(const float* __restrict__ y,
                                             const float* __restrict__ Wb,
                                             const float* __restrict__ bb,
                                             float* __restrict__ out) {
    int wid  = threadIdx.x >> 6;
    int lane = threadIdx.x & 63;
    int o = blockIdx.x * 4 + wid;                 // row of Wb (32 rows -> 8 blocks)
    const f32x4* wr = (const f32x4*)(Wb + (size_t)o * DH);
    const f32x4* yy = (const f32x4*)y;
    float acc = 0.0f;
#pragma unroll 8
    for (int it = 0; it < (DH / 4) / 64; ++it) {  // 64 iters
        int idx = it * 64 + lane;
        f32x4 w = wr[idx];
        f32x4 x = yy[idx];
        acc += w.x * x.x + w.y * x.y + w.z * x.z + w.w * x.w;
    }
#pragma unroll
    for (int off = 32; off > 0; off >>= 1) acc += __shfl_down(acc, off, 64);
    if (lane == 0) out[o] = tanhf(acc + bb[o]);
}

// ---------------------------------------------------------------------------

extern "C" void kernel_launch(void* const* d_in, const int* in_sizes, int n_in,
                              void* d_out, int out_size, void* d_ws, size_t ws_size,
                              hipStream_t stream) {
    const float* data = (const float*)d_in[0];
    const int*   edge = (const int*)d_in[1];       // [2, E] int32
    const float* W1   = (const float*)d_in[2];
    const float* b1   = (const float*)d_in[3];
    const float* W2   = (const float*)d_in[4];
    const float* b2   = (const float*)d_in[5];
    const float* W3   = (const float*)d_in[6];
    const float* b3   = (const float*)d_in[7];
    const float* Wa   = (const float*)d_in[8];
    const float* ba   = (const float*)d_in[9];
    const float* Wb   = (const float*)d_in[10];
    const float* bb   = (const float*)d_in[11];
    float* out = (float*)d_out;

    const int* src = edge;
    const int* dst = edge + NE;

    // workspace layout
    char* ws = (char*)d_ws;
    int*   cnt    = (int*)ws;                      // [NN]   (zeroed in P0)
    int*   row    = cnt + NN;                      // [NN+1]
    int*   cursor = row + NN + 1;                  // [NN]
    int*   srcs   = cursor + NN;                   // [NE]
    float* dinv   = (float*)(srcs + NE);           // [NN]
    float* h1     = dinv + NN;                     // [NN*4]
    float* h2     = h1 + NN * 4;                   // [NN*2]
    float* h3     = h2 + NN * 2;                   // [NN]
    float* v      = h3 + NN;                       // [NN]
    float* y1     = v + NN;                        // [DH]

    void* args[] = {
        (void*)&data, (void*)&W1, (void*)&b1, (void*)&W2, (void*)&b2,
        (void*)&W3, (void*)&b3, (void*)&src, (void*)&dst,
        (void*)&cnt, (void*)&row, (void*)&cursor, (void*)&srcs,
        (void*)&dinv, (void*)&h1, (void*)&h2, (void*)&h3, (void*)&v
    };
    hipLaunchCooperativeKernel((const void*)k_gcn, dim3(NBLK), dim3(NTHR),
                               args, 0, stream);

    k_mv1<<<dim3(DH / 4), dim3(256), 0, stream>>>(v, Wa, ba, y1);
    k_mv2<<<dim3(NOUT / 4), dim3(256), 0, stream>>>(y1, Wb, bb, out);
}